// Round 9
// baseline (1183.252 us; speedup 1.0000x reference)
//
#include <hip/hip_runtime.h>

// Problem constants (B=8, N=4096, n_points=1024, n_samples=32, D_PTS=6, MLPS=[64,64,128])
#define NPTS  4096
#define NB    8
#define NC    1024
#define NSAMP 32
#define DP    6
#define C0    9      // 3 + D_PTS
#define C3    128
#define ROWS_TOT 262144   // NB*NC*NSAMP

// Workspace layout (bytes).
#define OFF_SS   (32ull<<10)     // 3 layers x {scale[128], shift[128]}
#define OFF_H0   (1ull<<20)      // h0: 262144 x 9 f32 (9.4 MB)
#define OFF_PSUM (168ull<<20)    // per-block channel sums   [C][NBLK] (max 4 MB)
#define OFF_PSQ  (172ull<<20)    // per-block channel sumsq  [C][NBLK] (max 4 MB)
#define OFF_GMX  (176ull<<20)    // per-centroid channel max [8192][128] (4 MB)
#define OFF_GMN  (180ull<<20)    // per-centroid channel min [8192][128] (4 MB)

typedef unsigned long long ull;

// Exact (no-FMA) squared distance to match numpy rounding; sum order ((x+y)+z).
__device__ __forceinline__ float sqdist_noc(float x, float y, float z,
                                            float cx, float cy, float cz) {
  #pragma clang fp contract(off)
  float dx = x - cx, dy = y - cy, dz = z - cz;
  return dx * dx + dy * dy + dz * dz;
}

// DPP move with old=self (masked/invalid lanes keep their value -> fmax identity)
template <int CTRL, int RM>
__device__ __forceinline__ float dpp_mov_f(float x) {
  int xi = __float_as_int(x);
  int r = __builtin_amdgcn_update_dpp(xi, xi, CTRL, RM, 0xf, false);
  return __int_as_float(r);
}

// Canonical gfx9 wave64 f32 max reduce; result valid in lane 63.
__device__ __forceinline__ float wave64_fmax(float x) {
  x = fmaxf(x, dpp_mov_f<0x111, 0xf>(x));  // row_shr:1
  x = fmaxf(x, dpp_mov_f<0x112, 0xf>(x));  // row_shr:2
  x = fmaxf(x, dpp_mov_f<0x114, 0xf>(x));  // row_shr:4
  x = fmaxf(x, dpp_mov_f<0x118, 0xf>(x));  // row_shr:8
  x = fmaxf(x, dpp_mov_f<0x142, 0xa>(x));  // row_bcast:15 -> rows 1,3
  x = fmaxf(x, dpp_mov_f<0x143, 0xc>(x));  // row_bcast:31 -> rows 2,3
  return x;
}

// ---------------------------------------------------------------------------
// FPS R9: TWO batches per block (512 thr, 8 waves). Waves 0-3 = batch A,
// 4-7 = batch B; each SIMD hosts one wave of each chain -> co-resident-wave
// latency hiding of the fold/barrier stalls (R8 ran 1 wave/SIMD, stalls
// exposed). Per-batch structure identical to R8: 16 pts/thr, tree argmax,
// f32 DPP reduce, coords+key published in parity exchange, 1 barrier/step.
// ---------------------------------------------------------------------------
__global__ __launch_bounds__(512)
void fps_kernel(const float* __restrict__ xyz, float* __restrict__ cent) {
  const int half = threadIdx.x >> 8;            // which batch chain
  const int t = threadIdx.x & 255;
  const int b = blockIdx.x * 2 + half;
  const float* X = xyz + (size_t)b * NPTS * 3;
  float* OC = cent + (size_t)b * NC * 3;

  __shared__ float4 sxyz[2][NPTS];              // 128 KB
  __shared__ float4 wkc[2][2][4];               // [half][parity][wave]
  __shared__ alignas(16) int wki[2][2][4];
  __shared__ int sidx[2][NC];                   // 8 KB

  for (int p = t; p < NPTS; p += 256)
    sxyz[half][p] = make_float4(X[p * 3 + 0], X[p * 3 + 1], X[p * 3 + 2], 0.f);
  __syncthreads();

  float px[16], py[16], pz[16], h[16];
  #pragma unroll
  for (int i = 0; i < 16; i++) {
    float4 v = sxyz[half][t * 16 + i];
    px[i] = v.x; py[i] = v.y; pz[i] = v.z;
    h[i] = fmaf(v.x, v.x, fmaf(v.y, v.y, v.z * v.z));   // |p|^2
  }

  const int wv = t >> 6;
  float4 c;   // current centroid (x,y,z,*)

  auto step_body = [&](int pw_) {
    const float c2x = c.x + c.x, c2y = c.y + c.y, c2z = c.z + c.z;
    float key[16]; int idx[16];
    #pragma unroll
    for (int i = 0; i < 16; i++) {
      key[i] = fmaf(pz[i], -c2z, fmaf(py[i], -c2y, fmaf(px[i], -c2x, h[i])));
      idx[i] = i;
    }
    #pragma unroll
    for (int s = 1; s < 16; s <<= 1) {          // tree argmax, first-max ties
      #pragma unroll
      for (int i = 0; i < 16; i += 2 * s) {
        bool tk = key[i + s] > key[i];
        key[i] = tk ? key[i + s] : key[i];
        idx[i] = tk ? idx[i + s] : idx[i];
      }
    }
    const float mx = key[0];
    const int mj = idx[0];
    float4 cand = sxyz[half][(t << 4) + mj];    // speculative; hides under reduce
    float wm = wave64_fmax(mx);
    float smax = __int_as_float(__builtin_amdgcn_readlane(__float_as_int(wm), 63));
    if (mx == smax) {
      wkc[half][pw_][wv] = make_float4(cand.x, cand.y, cand.z, smax);
      wki[half][pw_][wv] = (t << 4) + mj;
    }
  };

  auto fold = [&](int pr_) -> int {
    float4 q0 = wkc[half][pr_][0], q1 = wkc[half][pr_][1];
    float4 q2 = wkc[half][pr_][2], q3 = wkc[half][pr_][3];
    const int4 ii = *(const int4*)&wki[half][pr_][0];
    bool g1 = q1.w > q0.w; float4 ca = g1 ? q1 : q0; int ia = g1 ? ii.y : ii.x;
    bool g3 = q3.w > q2.w; float4 cb = g3 ? q3 : q2; int ib = g3 ? ii.w : ii.z;
    bool gb = cb.w > ca.w; c = gb ? cb : ca; return gb ? ib : ia;
  };

  // ---- iteration 1: selection 0 is point 0 (seed) ----
  if (t == 0) { sidx[half][0] = 0; }
  if (t == 0) { h[0] = -__builtin_inff(); }     // retire point 0 (t0 owns it)
  c = sxyz[half][0];
  step_body(1);
  __syncthreads();

  for (int k = 2; k < NC; k++) {
    const int pr = (k - 1) & 1, pw = k & 1;
    int gidx = fold(pr);                        // selection k-1
    if (t == 0) sidx[half][k - 1] = gidx;
    if ((gidx >> 4) == t) {                     // retire winner
      int m = gidx & 15;
      #pragma unroll
      for (int i = 0; i < 16; i++)
        if (i == m) h[i] = -__builtin_inff();
    }
    step_body(pw);
    __syncthreads();
  }
  {
    int gidx = fold(1023 & 1);
    if (t == 0) sidx[half][NC - 1] = gidx;
  }
  __syncthreads();
  for (int i = t; i < NC; i += 256) {           // one-shot centroid emit
    float4 cc = sxyz[half][sidx[half][i]];
    OC[i * 3 + 0] = cc.x;
    OC[i * 3 + 1] = cc.y;
    OC[i * 3 + 2] = cc.z;
  }
}

// ---------------------------------------------------------------------------
// query_ball + gather + concat (unchanged): exact stable-argsort semantics
// via the min(dist, r^2=0.04) quirk.
// ---------------------------------------------------------------------------
#define BCAP 256
__global__ __launch_bounds__(256)
void ball_kernel(const float* __restrict__ xyz, const float* __restrict__ pts,
                 const float* __restrict__ cent, float* __restrict__ h0) {
  const int blk = blockIdx.x;       // b*NC + c
  const int b = blk >> 10;
  const int t = threadIdx.x;
  const float* X = xyz + (size_t)b * NPTS * 3;
  const float* P = pts + (size_t)b * NPTS * DP;
  const float cx = cent[(size_t)blk * 3 + 0];
  const float cy = cent[(size_t)blk * 3 + 1];
  const float cz = cent[(size_t)blk * 3 + 2];

  __shared__ int scount;
  __shared__ ull skeys[BCAP];
  __shared__ ull ssorted[BCAP];
  __shared__ int sel[NSAMP];
  if (t == 0) scount = 0;
  __syncthreads();

  #pragma unroll
  for (int i = 0; i < 16; i++) {
    int j = t * 16 + i;
    float sq = sqdist_noc(X[j * 3 + 0], X[j * 3 + 1], X[j * 3 + 2], cx, cy, cz);
    if (sq < 0.0017f) {                       // conservative guard
      float d = (sq > 0.f) ? sqrtf(sq) : 0.f; // exact per-reference norm
      if (d < 0.04f) {                        // strictly inside the clip value
        int pos = atomicAdd(&scount, 1);
        if (pos < BCAP)
          skeys[pos] = ((ull)(unsigned)__float_as_int(d) << 12) | (unsigned)j;
      }
    }
  }
  __syncthreads();
  const int M = min(scount, BCAP);

  if (t < M) {                                // rank-sort inner set
    ull my = skeys[t];
    int r = 0;
    for (int j2 = 0; j2 < M; j2++) r += (skeys[j2] < my);
    ssorted[r] = my;
  }
  __syncthreads();

  if (t < NSAMP) {
    int v;
    if (t < M) {
      v = (int)(ssorted[t] & 0xFFFull);
    } else {
      int s = t - M;                          // s-th smallest non-inner index
      int idx = s;
      for (int it = 0; it < 40; it++) {
        int c = 0;
        for (int j2 = 0; j2 < M; j2++) c += ((int)(skeys[j2] & 0xFFFull) <= idx);
        int nidx = s + c;
        if (nidx == idx) break;
        idx = nidx;
      }
      v = idx;
    }
    sel[t] = v;
  }
  __syncthreads();

  float* H = h0 + (size_t)blk * NSAMP * C0;
  for (int e = t; e < NSAMP * C0; e += 256) {
    int k = e / C0;
    int c = e - k * C0;
    int j = sel[k];
    H[e] = (c < 3) ? X[j * 3 + c] : P[j * DP + (c - 3)];
  }
}

// ---------------------------------------------------------------------------
// pass0: h0 @ W0 + b0 -> y0 STATS ONLY (no y0 materialization). 64 rows/blk.
// ---------------------------------------------------------------------------
__global__ __launch_bounds__(256)
void pass0_kernel(const float* __restrict__ h0, const float* __restrict__ W,
                  const float* __restrict__ bias,
                  float* __restrict__ psum, float* __restrict__ psq) {
  __shared__ float xs[64 * C0];
  __shared__ float ws[C0 * 64];
  __shared__ float red[2][16][64];
  const int blk = blockIdx.x, t = threadIdx.x;
  const size_t rbase = (size_t)blk * 64;
  for (int e = t; e < 64 * C0; e += 256) xs[e] = h0[rbase * C0 + e];
  for (int e = t; e < C0 * 64; e += 256) ws[e] = W[e];
  __syncthreads();
  const int rg = t >> 4, cg = t & 15;
  float acc[4][4];
  float4 bv = *(const float4*)(bias + cg * 4);
  #pragma unroll
  for (int r = 0; r < 4; r++) { acc[r][0] = bv.x; acc[r][1] = bv.y; acc[r][2] = bv.z; acc[r][3] = bv.w; }
  #pragma unroll
  for (int k = 0; k < C0; k++) {
    float4 wv = *(const float4*)(ws + k * 64 + cg * 4);
    #pragma unroll
    for (int r = 0; r < 4; r++) {
      float x = xs[(rg * 4 + r) * C0 + k];
      acc[r][0] = fmaf(x, wv.x, acc[r][0]);
      acc[r][1] = fmaf(x, wv.y, acc[r][1]);
      acc[r][2] = fmaf(x, wv.z, acc[r][2]);
      acc[r][3] = fmaf(x, wv.w, acc[r][3]);
    }
  }
  #pragma unroll
  for (int c4 = 0; c4 < 4; c4++) {
    float s = 0.f, q = 0.f;
    #pragma unroll
    for (int r = 0; r < 4; r++) { float v = acc[r][c4]; s += v; q = fmaf(v, v, q); }
    red[0][rg][cg * 4 + c4] = s;
    red[1][rg][cg * 4 + c4] = q;
  }
  __syncthreads();
  if (t < 64) {
    float S = 0.f, Q = 0.f;
    #pragma unroll
    for (int g = 0; g < 16; g++) { S += red[0][g][t]; Q += red[1][g][t]; }
    psum[(size_t)t * 4096 + blk] = S;
    psq [(size_t)t * 4096 + blk] = Q;
  }
}

// ---------------------------------------------------------------------------
// pass1: h0 -> y0 (recompute, identical fma order) -> BN0+relu -> y1 STATS.
// 64 rows/block, 4096 blocks. No y materialization.
// ---------------------------------------------------------------------------
__global__ __launch_bounds__(256)
void pass1_kernel(const float* __restrict__ h0, const float* __restrict__ W0,
                  const float* __restrict__ b0, const float* __restrict__ ss0,
                  const float* __restrict__ W1, const float* __restrict__ b1,
                  float* __restrict__ psum, float* __restrict__ psq) {
  __shared__ float xs0[64 * C0];
  __shared__ float w0s[C0 * 64];
  __shared__ float x1[64 * 68];
  __shared__ float w1s[64 * 64];
  __shared__ float scs[64], shs[64];
  __shared__ float red[2][16][64];
  const int blk = blockIdx.x, t = threadIdx.x;
  const size_t rbase = (size_t)blk * 64;
  for (int e = t; e < 64 * C0; e += 256) xs0[e] = h0[rbase * C0 + e];
  for (int e = t; e < C0 * 64; e += 256) w0s[e] = W0[e];
  for (int e = t; e < 64 * 64; e += 256) w1s[e] = W1[e];
  if (t < 64) { scs[t] = ss0[t]; shs[t] = ss0[128 + t]; }
  __syncthreads();
  const int rg = t >> 4, cg = t & 15;
  {  // recompute y0 (same per-element arithmetic as pass0) -> x1
    float acc[4][4];
    float4 bv = *(const float4*)(b0 + cg * 4);
    #pragma unroll
    for (int r = 0; r < 4; r++) { acc[r][0] = bv.x; acc[r][1] = bv.y; acc[r][2] = bv.z; acc[r][3] = bv.w; }
    #pragma unroll
    for (int k = 0; k < C0; k++) {
      float4 wv = *(const float4*)(w0s + k * 64 + cg * 4);
      #pragma unroll
      for (int r = 0; r < 4; r++) {
        float x = xs0[(rg * 4 + r) * C0 + k];
        acc[r][0] = fmaf(x, wv.x, acc[r][0]);
        acc[r][1] = fmaf(x, wv.y, acc[r][1]);
        acc[r][2] = fmaf(x, wv.z, acc[r][2]);
        acc[r][3] = fmaf(x, wv.w, acc[r][3]);
      }
    }
    float4 sc = *(const float4*)(scs + cg * 4);
    float4 sh = *(const float4*)(shs + cg * 4);
    #pragma unroll
    for (int r = 0; r < 4; r++) {
      float4 o;
      o.x = fmaxf(fmaf(acc[r][0], sc.x, sh.x), 0.f);
      o.y = fmaxf(fmaf(acc[r][1], sc.y, sh.y), 0.f);
      o.z = fmaxf(fmaf(acc[r][2], sc.z, sh.z), 0.f);
      o.w = fmaxf(fmaf(acc[r][3], sc.w, sh.w), 0.f);
      *(float4*)(x1 + (rg * 4 + r) * 68 + cg * 4) = o;
    }
  }
  __syncthreads();
  // y1 = x1 @ W1 + b1 -> stats
  float acc[4][4];
  float4 bv = *(const float4*)(b1 + cg * 4);
  #pragma unroll
  for (int r = 0; r < 4; r++) { acc[r][0] = bv.x; acc[r][1] = bv.y; acc[r][2] = bv.z; acc[r][3] = bv.w; }
  for (int k0 = 0; k0 < 64; k0 += 4) {
    float4 xv[4];
    #pragma unroll
    for (int r = 0; r < 4; r++)
      xv[r] = *(const float4*)(x1 + (rg * 4 + r) * 68 + k0);
    #pragma unroll
    for (int kk = 0; kk < 4; kk++) {
      float4 wv = *(const float4*)(w1s + (k0 + kk) * 64 + cg * 4);
      #pragma unroll
      for (int r = 0; r < 4; r++) {
        float x = (&xv[r].x)[kk];
        acc[r][0] = fmaf(x, wv.x, acc[r][0]);
        acc[r][1] = fmaf(x, wv.y, acc[r][1]);
        acc[r][2] = fmaf(x, wv.z, acc[r][2]);
        acc[r][3] = fmaf(x, wv.w, acc[r][3]);
      }
    }
  }
  #pragma unroll
  for (int c4 = 0; c4 < 4; c4++) {
    float s = 0.f, q = 0.f;
    #pragma unroll
    for (int r = 0; r < 4; r++) { float v = acc[r][c4]; s += v; q = fmaf(v, v, q); }
    red[0][rg][cg * 4 + c4] = s;
    red[1][rg][cg * 4 + c4] = q;
  }
  __syncthreads();
  if (t < 64) {
    float S = 0.f, Q = 0.f;
    #pragma unroll
    for (int g = 0; g < 16; g++) { S += red[0][g][t]; Q += red[1][g][t]; }
    psum[(size_t)t * 4096 + blk] = S;
    psq [(size_t)t * 4096 + blk] = Q;
  }
}

// ---------------------------------------------------------------------------
// pass2: h0 -> y0 -> BN0relu -> y1 -> BN1relu -> y2 stats + per-centroid
// max/min of raw y2. 32 rows/block (= one centroid), 8192 blocks.
// ---------------------------------------------------------------------------
__global__ __launch_bounds__(256)
void pass2_kernel(const float* __restrict__ h0, const float* __restrict__ W0,
                  const float* __restrict__ b0, const float* __restrict__ ss0,
                  const float* __restrict__ W1, const float* __restrict__ b1,
                  const float* __restrict__ ss1, const float* __restrict__ W2,
                  const float* __restrict__ bias2,
                  float* __restrict__ psum, float* __restrict__ psq,
                  float* __restrict__ gmax, float* __restrict__ gmin) {
  __shared__ float xs0[32 * C0];
  __shared__ float w0s[C0 * 64];
  __shared__ float b0s[64], b1s[64];
  __shared__ float sc0[64], sh0[64], sc1[64], sh1[64];
  __shared__ float x1[32 * 68];
  __shared__ float w1s[64 * 64];
  __shared__ float x2[32 * 68];
  __shared__ float w2s[64 * C3];
  __shared__ float red[2][8][C3];
  __shared__ float redm[2][8][C3];
  const int blk = blockIdx.x, t = threadIdx.x;
  const size_t rbase = (size_t)blk * 32;
  for (int e = t; e < 32 * C0; e += 256) xs0[e] = h0[rbase * C0 + e];
  for (int e = t; e < C0 * 64; e += 256) w0s[e] = W0[e];
  for (int e = t; e < 64 * 64; e += 256) w1s[e] = W1[e];
  for (int e = t; e < 64 * C3; e += 256) w2s[e] = W2[e];
  if (t < 64) {
    b0s[t] = b0[t]; b1s[t] = b1[t];
    sc0[t] = ss0[t]; sh0[t] = ss0[128 + t];
    sc1[t] = ss1[t]; sh1[t] = ss1[128 + t];
  }
  __syncthreads();
  const int row = t >> 3, c8 = (t & 7) * 8;
  {  // y0 -> x1 (k ascending fmaf == pass0/pass1 arithmetic)
    float a[8];
    #pragma unroll
    for (int j = 0; j < 8; j++) a[j] = b0s[c8 + j];
    #pragma unroll
    for (int k = 0; k < C0; k++) {
      float xv = xs0[row * C0 + k];
      #pragma unroll
      for (int j = 0; j < 8; j++) a[j] = fmaf(xv, w0s[k * 64 + c8 + j], a[j]);
    }
    #pragma unroll
    for (int j = 0; j < 8; j++)
      x1[row * 68 + c8 + j] = fmaxf(fmaf(a[j], sc0[c8 + j], sh0[c8 + j]), 0.f);
  }
  __syncthreads();
  {  // y1 -> x2 (k ascending == pass1 arithmetic)
    float a[8];
    #pragma unroll
    for (int j = 0; j < 8; j++) a[j] = b1s[c8 + j];
    for (int k = 0; k < 64; k++) {
      float xv = x1[row * 68 + k];
      #pragma unroll
      for (int j = 0; j < 8; j++) a[j] = fmaf(xv, w1s[k * 64 + c8 + j], a[j]);
    }
    #pragma unroll
    for (int j = 0; j < 8; j++)
      x2[row * 68 + c8 + j] = fmaxf(fmaf(a[j], sc1[c8 + j], sh1[c8 + j]), 0.f);
  }
  __syncthreads();
  // y2 = x2 @ W2 + b2: stats + per-centroid max/min (no materialization)
  const int rg = t / 32, cg = t % 32;
  float acc[4][4];
  float4 bv = *(const float4*)(bias2 + cg * 4);
  #pragma unroll
  for (int r = 0; r < 4; r++) { acc[r][0] = bv.x; acc[r][1] = bv.y; acc[r][2] = bv.z; acc[r][3] = bv.w; }
  for (int k0 = 0; k0 < 64; k0 += 4) {
    float4 xv[4];
    #pragma unroll
    for (int r = 0; r < 4; r++)
      xv[r] = *(const float4*)(x2 + (rg * 4 + r) * 68 + k0);
    #pragma unroll
    for (int kk = 0; kk < 4; kk++) {
      float4 wv = *(const float4*)(w2s + (k0 + kk) * C3 + cg * 4);
      #pragma unroll
      for (int r = 0; r < 4; r++) {
        float x = (&xv[r].x)[kk];
        acc[r][0] = fmaf(x, wv.x, acc[r][0]);
        acc[r][1] = fmaf(x, wv.y, acc[r][1]);
        acc[r][2] = fmaf(x, wv.z, acc[r][2]);
        acc[r][3] = fmaf(x, wv.w, acc[r][3]);
      }
    }
  }
  #pragma unroll
  for (int c4 = 0; c4 < 4; c4++) {
    float s = 0.f, q = 0.f;
    float mx = acc[0][c4], mn = acc[0][c4];
    #pragma unroll
    for (int r = 0; r < 4; r++) {
      float v = acc[r][c4];
      s += v; q = fmaf(v, v, q);
      if (r) { mx = fmaxf(mx, v); mn = fminf(mn, v); }
    }
    red[0][rg][cg * 4 + c4] = s;
    red[1][rg][cg * 4 + c4] = q;
    redm[0][rg][cg * 4 + c4] = mx;
    redm[1][rg][cg * 4 + c4] = mn;
  }
  __syncthreads();
  if (t < C3) {
    float S = 0.f, Q = 0.f;
    #pragma unroll
    for (int g = 0; g < 8; g++) { S += red[0][g][t]; Q += red[1][g][t]; }
    psum[(size_t)t * 8192 + blk] = S;
    psq [(size_t)t * 8192 + blk] = Q;
    float mx = redm[0][0][t], mn = redm[1][0][t];
    #pragma unroll
    for (int g = 1; g < 8; g++) { mx = fmaxf(mx, redm[0][g][t]); mn = fminf(mn, redm[1][g][t]); }
    gmax[(size_t)blk * C3 + t] = mx;
    gmin[(size_t)blk * C3 + t] = mn;
  }
}

// ---------------------------------------------------------------------------
// stats finalize (unchanged)
// ---------------------------------------------------------------------------
template <int NBLK>
__global__ __launch_bounds__(256)
void stats_final_kernel(const float* __restrict__ psum, const float* __restrict__ psq,
                        const float* __restrict__ g, const float* __restrict__ be,
                        float* __restrict__ ss_out) {
  const int c = blockIdx.x, t = threadIdx.x;
  float S = 0.f, Q = 0.f;
  for (int i = t; i < NBLK; i += 256) {
    S += psum[(size_t)c * NBLK + i];
    Q += psq [(size_t)c * NBLK + i];
  }
  __shared__ float sS[256], sQ[256];
  sS[t] = S; sQ[t] = Q;
  __syncthreads();
  #pragma unroll
  for (int off = 128; off; off >>= 1) {
    if (t < off) { sS[t] += sS[t + off]; sQ[t] += sQ[t + off]; }
    __syncthreads();
  }
  if (t == 0) {
    const float inv = 1.0f / 262144.0f;
    float mean = sS[0] * inv;
    float var = sQ[0] * inv - mean * mean;
    float scale = g[c] / sqrtf(var + 1e-3f);
    ss_out[c] = scale;
    ss_out[128 + c] = be[c] - mean * scale;
  }
}

// pool finalize (unchanged)
__global__ __launch_bounds__(128)
void pool_final_kernel(const float* __restrict__ gmax, const float* __restrict__ gmin,
                       const float* __restrict__ ss2, float* __restrict__ out1) {
  const int blk = blockIdx.x, c = threadIdx.x;
  const float sc = ss2[c], sh = ss2[128 + c];
  float v = (sc >= 0.f) ? gmax[(size_t)blk * C3 + c] : gmin[(size_t)blk * C3 + c];
  out1[(size_t)blk * C3 + c] = fmaxf(fmaf(v, sc, sh), 0.f);
}

extern "C" void kernel_launch(void* const* d_in, const int* in_sizes, int n_in,
                              void* d_out, int out_size, void* d_ws, size_t ws_size,
                              hipStream_t stream) {
  const float* xyz = (const float*)d_in[0];
  const float* pts = (const float*)d_in[1];
  const float* w0 = (const float*)d_in[2];
  const float* b0 = (const float*)d_in[3];
  const float* g0 = (const float*)d_in[4];
  const float* be0 = (const float*)d_in[5];
  const float* w1 = (const float*)d_in[6];
  const float* b1 = (const float*)d_in[7];
  const float* g1 = (const float*)d_in[8];
  const float* be1 = (const float*)d_in[9];
  const float* w2 = (const float*)d_in[10];
  const float* b2 = (const float*)d_in[11];
  const float* g2 = (const float*)d_in[12];
  const float* be2 = (const float*)d_in[13];

  float* out = (float*)d_out;
  float* cent = out;                       // [8,1024,3]
  float* out1 = out + (size_t)NB * NC * 3; // [8,1024,128]

  char* ws = (char*)d_ws;
  float* ssA  = (float*)(ws + OFF_SS);
  float* h0   = (float*)(ws + OFF_H0);
  float* psum = (float*)(ws + OFF_PSUM);
  float* psq  = (float*)(ws + OFF_PSQ);
  float* gmx  = (float*)(ws + OFF_GMX);
  float* gmn  = (float*)(ws + OFF_GMN);

  fps_kernel<<<dim3(NB / 2), dim3(512), 0, stream>>>(xyz, cent);
  ball_kernel<<<dim3(NB * NC), dim3(256), 0, stream>>>(xyz, pts, cent, h0);

  pass0_kernel<<<dim3(ROWS_TOT / 64), dim3(256), 0, stream>>>(h0, w0, b0, psum, psq);
  stats_final_kernel<4096><<<dim3(64), dim3(256), 0, stream>>>(psum, psq, g0, be0, ssA + 0 * 256);

  pass1_kernel<<<dim3(ROWS_TOT / 64), dim3(256), 0, stream>>>(
      h0, w0, b0, ssA + 0 * 256, w1, b1, psum, psq);
  stats_final_kernel<4096><<<dim3(64), dim3(256), 0, stream>>>(psum, psq, g1, be1, ssA + 1 * 256);

  pass2_kernel<<<dim3(ROWS_TOT / 32), dim3(256), 0, stream>>>(
      h0, w0, b0, ssA + 0 * 256, w1, b1, ssA + 1 * 256, w2, b2, psum, psq, gmx, gmn);
  stats_final_kernel<8192><<<dim3(128), dim3(256), 0, stream>>>(psum, psq, g2, be2, ssA + 2 * 256);

  pool_final_kernel<<<dim3(NB * NC), dim3(128), 0, stream>>>(gmx, gmn, ssA + 2 * 256, out1);

  (void)in_sizes; (void)n_in; (void)out_size; (void)ws_size;
}